// Round 3
// baseline (1612.132 us; speedup 1.0000x reference)
//
#include <hip/hip_runtime.h>

// Seq2SeqRNN v8: LDS diet. v5/v6/v7 all ~1100-1200us with identical per-step LDS
// traffic (~312 KB/step/CU = ~3700 cyc at 85 B/cyc ds_read_b128 ceiling) -> LDS
// throughput is the invariant bottleneck. v8:
//  (1) A-frags hoisted out of ti loop (single k-pass, 6 MFMAs/chunk): 176->88 KB
//  (2) WL LDS buffer deleted; all non-reg B-frags streamed from fragment-linear
//      ws image with 3-buffer distance-2 chunk lookahead: 128->0 KB
//  (3) wfr = 4 chunks (96 regs) + 32 acc = 128-reg half; stream pipe fits VGPRs.
// LDS/step ~96 KB (-69%). Barrier/prefetch/decode-fb structure = v7 (proven).

#define BATCH 512
#define TSEQ  192
#define LIN_  96
#define LOUT_ 96
#define NUM_  64
#define EMB_  32
#define HID_  256
#define INS_  96

#define NBLK  32
#define NT    512          // 8 waves, 2/SIMD

// XH row layout (us cols): [fb/num0 64 | num1 64 | e0 32 | e1 32 | h0 256 | h1 256]
#define XSTR  712
#define XFB   0
#define XNUM0 0
#define XNUM1 64
#define XEMB0 128
#define XEMB1 160
#define XHB   192          // h buf0 @192, buf1 @448

// ws: fragment-linear bf16 images, 1024 B per frag (lane l -> bytes l*16..+16).
// Stream frags: per tt (0..15), 21 frags: [r c4..10: slot 0..6][z: 7..13][n c4..10: 14..20]
//   -> 336 frags = 344064 B.  WD frags: fid = tt*8 + c (tt<4, c<8) -> 32 frags.
#define WS_STR  0u
#define WS_WD   344064u
#define WS_NEED 376832u

typedef __attribute__((ext_vector_type(8))) short short8_t;
typedef __attribute__((ext_vector_type(4))) float float4_t;
typedef unsigned short us;

__device__ __forceinline__ us f2bf(float x) {
    unsigned u = __builtin_bit_cast(unsigned, x);
    u = (u + 0x7FFFu + ((u >> 16) & 1u)) >> 16;
    return (us)u;
}
__device__ __forceinline__ float sigm(float x)  { return 1.0f / (1.0f + __expf(-x)); }
__device__ __forceinline__ float tanhx(float x) { return 2.0f / (1.0f + __expf(-2.0f * x)) - 1.0f; }

__device__ __forceinline__ short8_t pack8(const float* v) {
    short8_t s;
    #pragma unroll
    for (int j = 0; j < 8; ++j) s[j] = (short)f2bf(v[j]);
    return s;
}

#define MFMA16(a, b, c) __builtin_amdgcn_mfma_f32_16x16x32_bf16((a), (b), (c), 0, 0, 0)

// ============ prep: fragment-linear bf16 weight images (stream + W_dec) ============
__global__ void prep_v8(const float* __restrict__ W_hh, const float* __restrict__ W_dec,
                        unsigned char* __restrict__ ws) {
    us* WSi = (us*)(ws + WS_STR);
    us* WDi = (us*)(ws + WS_WD);
    const int idx = blockIdx.x * 256 + threadIdx.x;
    if (idx >= 368 * 64) return;
    const int f = idx >> 6, l = idx & 63;
    const int r16 = l & 15, kq8 = (l >> 4) * 8;
    float tmp[8];
    if (f < 336) {
        const int tt = f / 21, slot = f % 21;
        const int g  = (slot < 7) ? 0 : (slot < 14 ? 1 : 2);
        const int cs = slot - g * 7;
        const int grow = g * 256 + tt * 16 + r16;
        const int k = (4 + cs) * 32 + kq8;          // 128..351, all >= 96 -> W_hh
        #pragma unroll
        for (int j = 0; j < 8; ++j) tmp[j] = W_hh[(size_t)grow * HID_ + (k - INS_) + j];
        *(short8_t*)(WSi + (size_t)f * 512 + l * 8) = pack8(tmp);
    } else {
        const int f3 = f - 336, tt = f3 >> 3, c = f3 & 7;
        const int urow = tt * 16 + r16, k = c * 32 + kq8;
        #pragma unroll
        for (int j = 0; j < 8; ++j) tmp[j] = W_dec[(size_t)urow * HID_ + k + j];
        *(short8_t*)(WDi + (size_t)f3 * 512 + l * 8) = pack8(tmp);
    }
}

// ============ main: one self-sufficient block per 16 batch rows ============
__global__ __launch_bounds__(NT, 2) void gru_v8(
    const float* __restrict__ input_num, const int* __restrict__ input_cat,
    const float* __restrict__ emb_table,
    const float* __restrict__ W_ih, const float* __restrict__ W_hh,
    const float* __restrict__ b_ih, const float* __restrict__ b_hh,
    const float* __restrict__ b_dec,
    const unsigned char* __restrict__ ws, float* __restrict__ out)
{
    __shared__ __align__(16) us XH[16 * XSTR];   // the ONLY LDS buffer now (~23 KB)

    const us* WSf = (const us*)(ws + WS_STR);
    const us* WDf = (const us*)(ws + WS_WD);

    const int t = threadIdx.x, wave = t >> 6, lane = t & 63;
    const int arow = lane & 15, quad = lane >> 4, kq = quad * 8;
    const int bb = blockIdx.x * 16;
    const int tt0 = 2 * wave, tt1 = 2 * wave + 1;

    // ---- one-time: reg gate-weight frags, chunks 0..3 (96 regs) ----
    // c0,c1 = num (W_ih k 0..63), c2 = emb (W_ih k 64..95), c3 = h (W_hh k 0..31)
    short8_t wfr[2][3][4];
    #pragma unroll
    for (int ti = 0; ti < 2; ++ti) {
        #pragma unroll
        for (int g3 = 0; g3 < 3; ++g3) {
            const int grow = g3 * HID_ + 32 * wave + 16 * ti + arow;
            #pragma unroll
            for (int kc = 0; kc < 4; ++kc) {
                float tmp[8];
                #pragma unroll
                for (int j2 = 0; j2 < 2; ++j2) {
                    const int k = kc * 32 + kq + j2 * 4;   // < 128; never straddles 96
                    float4 v = (k < INS_)
                        ? *(const float4*)&W_ih[(size_t)grow * INS_ + k]
                        : *(const float4*)&W_hh[(size_t)grow * HID_ + (k - INS_)];
                    tmp[j2 * 4 + 0] = v.x; tmp[j2 * 4 + 1] = v.y;
                    tmp[j2 * 4 + 2] = v.z; tmp[j2 * 4 + 3] = v.w;
                }
                wfr[ti][g3][kc] = pack8(tmp);
            }
        }
    }

    for (int c = t; c < 16 * XSTR; c += NT) XH[c] = 0;

    // ---- biases ----
    float bRr[2], bZr[2], bNXr[2], bNHr[2];
    #pragma unroll
    for (int ti = 0; ti < 2; ++ti) {
        const int u = 32 * wave + 16 * ti + arow;
        bRr[ti]  = b_ih[u] + b_hh[u];
        bZr[ti]  = b_ih[HID_ + u] + b_hh[HID_ + u];
        bNXr[ti] = b_ih[2 * HID_ + u];
        bNHr[ti] = b_hh[2 * HID_ + u];
    }
    const float bdr = (wave < 4) ? b_dec[wave * 16 + arow] : 0.0f;
    float hr[2][4] = {{0.f,0.f,0.f,0.f},{0.f,0.f,0.f,0.f}};

    // ---- staging roles + initial stage of x_0 ----
    const int srow = t >> 4, sq = t & 15;                    // num role: t<256
    const int erow = (t - 256) >> 3, eq = (t - 256) & 7;     // emb role: 256<=t<384
    const bool isN = (t < 256), isE = (t >= 256 && t < 384);
    float4 pnum = {0.f,0.f,0.f,0.f}, pemb = {0.f,0.f,0.f,0.f};
    int pcat = 0;

    if (isN) {
        float4 v = *(const float4*)&input_num[((size_t)(bb + srow) * TSEQ + 0) * NUM_ + sq * 4];
        ushort4 s4 = { f2bf(v.x), f2bf(v.y), f2bf(v.z), f2bf(v.w) };
        *(ushort4*)&XH[srow * XSTR + XNUM0 + sq * 4] = s4;
    } else if (isE) {
        const int c0 = input_cat[(bb + erow) * TSEQ + 0];
        float4 v = *(const float4*)&emb_table[(size_t)c0 * EMB_ + eq * 4];
        ushort4 s4 = { f2bf(v.x), f2bf(v.y), f2bf(v.z), f2bf(v.w) };
        *(ushort4*)&XH[erow * XSTR + XEMB0 + eq * 4] = s4;
        pcat = input_cat[(bb + erow) * TSEQ + 1];
    }
    __syncthreads();

    // ======== 191 sequential GRU steps ========
    for (int sg = 1; sg <= 191; ++sg) {
        const int bx = (sg - 1) & 1, hn = sg & 1;
        const int hbase = XHB + ((sg - 1) & 1) * 256;
        float oval[4];

        if (sg <= 96) {
            // encoder: prefetch at step-top (full step of slack before drain)
            if (isN && sg <= 95)
                pnum = *(const float4*)&input_num[((size_t)(bb + srow) * TSEQ + sg) * NUM_ + sq * 4];
            if (isE) {
                pemb = *(const float4*)&emb_table[(size_t)pcat * EMB_ + eq * 4];
                pcat = input_cat[(bb + erow) * TSEQ + sg + 1];
            }
        } else {
            // decode fb-projection: out_prev = h_prev @ W_dec^T (waves 0..3)
            if (wave < 4) {
                short8_t wd[8];
                #pragma unroll
                for (int c = 0; c < 8; ++c)
                    wd[c] = *(const short8_t*)&WDf[(size_t)(wave * 8 + c) * 512 + lane * 8];
                float4_t acc = {0.f,0.f,0.f,0.f};
                #pragma unroll
                for (int c = 0; c < 8; ++c) {
                    short8_t a = *(const short8_t*)&XH[arow * XSTR + hbase + c * 32 + kq];
                    acc = MFMA16(a, wd[c], acc);
                }
                #pragma unroll
                for (int i = 0; i < 4; ++i) {
                    oval[i] = acc[i] + bdr;
                    XH[(quad * 4 + i) * XSTR + XFB + wave * 16 + arow] = f2bf(oval[i]);
                }
            }
            __syncthreads();   // B2: feedback visible
            if (wave < 4) {    // out store after B2: drains at B3 with gate slack
                const int cg = wave * 16 + arow, pos = sg - 97;
                #pragma unroll
                for (int i = 0; i < 4; ++i)
                    out[((size_t)(bb + quad * 4 + i) * LOUT_ + pos) * NUM_ + cg] = oval[i];
            }
            if (isE && sg <= 190) {
                pemb = *(const float4*)&emb_table[(size_t)pcat * EMB_ + eq * 4];
                if (sg <= 189) pcat = input_cat[(bb + erow) * TSEQ + sg + 1];
            }
        }

        // ---- gates: single k-pass, ti-interleaved (A read ONCE per chunk) ----
        const int xc01 = (sg <= 96) ? (XNUM0 + bx * 64) : XFB;
        const int xc2  = XEMB0 + bx * 32;

        float4_t aR[2]  = {{0.f,0.f,0.f,0.f},{0.f,0.f,0.f,0.f}};
        float4_t aZ[2]  = {{0.f,0.f,0.f,0.f},{0.f,0.f,0.f,0.f}};
        float4_t aNX[2] = {{0.f,0.f,0.f,0.f},{0.f,0.f,0.f,0.f}};
        float4_t aNH[2] = {{0.f,0.f,0.f,0.f},{0.f,0.f,0.f,0.f}};

        // stream pipeline: 3 buffers, distance-2 lookahead. slot: r=cs, z=7+cs, n=14+cs
        short8_t sv[3][6];   // [buf][ti*3 + gate]
        #pragma unroll
        for (int p = 0; p < 2; ++p) {   // issue chunks c4 (cs=0), c5 (cs=1)
            sv[p][0] = *(const short8_t*)&WSf[(size_t)(tt0 * 21 + 0  + p) * 512 + lane * 8];
            sv[p][1] = *(const short8_t*)&WSf[(size_t)(tt0 * 21 + 7  + p) * 512 + lane * 8];
            sv[p][2] = *(const short8_t*)&WSf[(size_t)(tt0 * 21 + 14 + p) * 512 + lane * 8];
            sv[p][3] = *(const short8_t*)&WSf[(size_t)(tt1 * 21 + 0  + p) * 512 + lane * 8];
            sv[p][4] = *(const short8_t*)&WSf[(size_t)(tt1 * 21 + 7  + p) * 512 + lane * 8];
            sv[p][5] = *(const short8_t*)&WSf[(size_t)(tt1 * 21 + 14 + p) * 512 + lane * 8];
        }

        // reg chunks c0..3 (A read once, both ti consume)
        #pragma unroll
        for (int kc = 0; kc < 4; ++kc) {
            const int xo = (kc < 2) ? (xc01 + kc * 32) : ((kc == 2) ? xc2 : hbase);
            short8_t a = *(const short8_t*)&XH[arow * XSTR + xo + kq];
            #pragma unroll
            for (int ti = 0; ti < 2; ++ti) {
                aR[ti] = MFMA16(a, wfr[ti][0][kc], aR[ti]);
                aZ[ti] = MFMA16(a, wfr[ti][1][kc], aZ[ti]);
                if (kc < 3) aNX[ti] = MFMA16(a, wfr[ti][2][kc], aNX[ti]);
                else        aNH[ti] = MFMA16(a, wfr[ti][2][kc], aNH[ti]);
            }
        }

        // stream chunks c4..10 (cs = 0..6); issue cs+2 before consuming cs
        #pragma unroll
        for (int cs = 0; cs < 7; ++cs) {
            if (cs < 5) {
                const int p = (cs + 2) % 3, c2 = cs + 2;
                sv[p][0] = *(const short8_t*)&WSf[(size_t)(tt0 * 21 + 0  + c2) * 512 + lane * 8];
                sv[p][1] = *(const short8_t*)&WSf[(size_t)(tt0 * 21 + 7  + c2) * 512 + lane * 8];
                sv[p][2] = *(const short8_t*)&WSf[(size_t)(tt0 * 21 + 14 + c2) * 512 + lane * 8];
                sv[p][3] = *(const short8_t*)&WSf[(size_t)(tt1 * 21 + 0  + c2) * 512 + lane * 8];
                sv[p][4] = *(const short8_t*)&WSf[(size_t)(tt1 * 21 + 7  + c2) * 512 + lane * 8];
                sv[p][5] = *(const short8_t*)&WSf[(size_t)(tt1 * 21 + 14 + c2) * 512 + lane * 8];
            }
            const int b = cs % 3;
            short8_t a = *(const short8_t*)&XH[arow * XSTR + hbase + (cs + 1) * 32 + kq];
            aR[0]  = MFMA16(a, sv[b][0], aR[0]);
            aZ[0]  = MFMA16(a, sv[b][1], aZ[0]);
            aNH[0] = MFMA16(a, sv[b][2], aNH[0]);
            aR[1]  = MFMA16(a, sv[b][3], aR[1]);
            aZ[1]  = MFMA16(a, sv[b][4], aZ[1]);
            aNH[1] = MFMA16(a, sv[b][5], aNH[1]);
        }

        // pointwise GRU cell
        #pragma unroll
        for (int ti = 0; ti < 2; ++ti) {
            #pragma unroll
            for (int i = 0; i < 4; ++i) {
                const float r = sigm(aR[ti][i] + bRr[ti]);
                const float z = sigm(aZ[ti][i] + bZr[ti]);
                const float n = tanhx(aNX[ti][i] + bNXr[ti] + r * (aNH[ti][i] + bNHr[ti]));
                hr[ti][i] = (1.0f - z) * n + z * hr[ti][i];
            }
        }

        // ---- write h[hn] + stage x_{sg} ----
        #pragma unroll
        for (int ti = 0; ti < 2; ++ti) {
            #pragma unroll
            for (int i = 0; i < 4; ++i)
                XH[(quad * 4 + i) * XSTR + XHB + hn * 256 + 32 * wave + 16 * ti + arow] = f2bf(hr[ti][i]);
        }
        if (sg <= 190) {
            if (isN && sg <= 95) {
                ushort4 s4 = { f2bf(pnum.x), f2bf(pnum.y), f2bf(pnum.z), f2bf(pnum.w) };
                *(ushort4*)&XH[srow * XSTR + XNUM0 + (sg & 1) * 64 + sq * 4] = s4;
            } else if (isE) {
                ushort4 s4 = { f2bf(pemb.x), f2bf(pemb.y), f2bf(pemb.z), f2bf(pemb.w) };
                *(ushort4*)&XH[erow * XSTR + XEMB0 + (sg & 1) * 32 + eq * 4] = s4;
            }
        }
        __syncthreads();   // B3 (single barrier for encoder steps)
    }

    // ======== epilogue: out position 95 from h_191 (h buf 1) ========
    if (wave < 4) {
        float4_t acc = {0.f,0.f,0.f,0.f};
        #pragma unroll
        for (int c = 0; c < 8; ++c) {
            short8_t wd = *(const short8_t*)&WDf[(size_t)(wave * 8 + c) * 512 + lane * 8];
            short8_t a  = *(const short8_t*)&XH[arow * XSTR + XHB + 256 + c * 32 + kq];
            acc = MFMA16(a, wd, acc);
        }
        const int cg = wave * 16 + arow;
        #pragma unroll
        for (int i = 0; i < 4; ++i)
            out[((size_t)(bb + quad * 4 + i) * LOUT_ + 95) * NUM_ + cg] = acc[i] + bdr;
    }
}

// ============ fallback (v1 logic, known-passing fp32) if ws too small ============
__global__ __launch_bounds__(512) void gru_fallback(
    const float* __restrict__ input_num, const int* __restrict__ input_cat,
    const float* __restrict__ emb_table,
    const float* __restrict__ W_ih, const float* __restrict__ W_hh,
    const float* __restrict__ b_ih, const float* __restrict__ b_hh,
    const float* __restrict__ W_dec, const float* __restrict__ b_dec,
    float* __restrict__ out)
{
    __shared__ __align__(16) float xh[4][352];
    __shared__ float wdec[NUM_ * 257];
    const int t = threadIdx.x, bbase = blockIdx.x * 4;
    const int u = t & 255, rb = (t >> 8) * 2;
    for (int i = t; i < NUM_ * HID_; i += 512) wdec[(i >> 8) * 257 + (i & 255)] = W_dec[i];
    for (int i = t; i < 4 * HID_; i += 512) xh[i >> 8][INS_ + (i & 255)] = 0.0f;
    const float bR = b_ih[u] + b_hh[u], bZ = b_ih[256 + u] + b_hh[256 + u];
    const float bNX = b_ih[512 + u], bNH = b_hh[512 + u], bD = b_dec[t & 63];
    __syncthreads();
    auto step = [&]() {
        float aR0 = bR, aR1 = bR, aZ0 = bZ, aZ1 = bZ, aNX0 = bNX, aNX1 = bNX, aNH0 = bNH, aNH1 = bNH;
        const float* x0 = xh[rb]; const float* x1 = xh[rb + 1];
        for (int kb = 0; kb < 88; ++kb) {
            float4 w0, w1, w2; int k4 = kb * 4;
            if (k4 < INS_) {
                w0 = *(const float4*)&W_ih[(size_t)u * INS_ + k4];
                w1 = *(const float4*)&W_ih[(size_t)(256 + u) * INS_ + k4];
                w2 = *(const float4*)&W_ih[(size_t)(512 + u) * INS_ + k4];
            } else {
                int kh = k4 - INS_;
                w0 = *(const float4*)&W_hh[(size_t)u * HID_ + kh];
                w1 = *(const float4*)&W_hh[(size_t)(256 + u) * HID_ + kh];
                w2 = *(const float4*)&W_hh[(size_t)(512 + u) * HID_ + kh];
            }
            float4 a = *(const float4*)&x0[k4], c = *(const float4*)&x1[k4];
            aR0 += w0.x*a.x+w0.y*a.y+w0.z*a.z+w0.w*a.w; aR1 += w0.x*c.x+w0.y*c.y+w0.z*c.z+w0.w*c.w;
            aZ0 += w1.x*a.x+w1.y*a.y+w1.z*a.z+w1.w*a.w; aZ1 += w1.x*c.x+w1.y*c.y+w1.z*c.z+w1.w*c.w;
            if (k4 < INS_) { aNX0 += w2.x*a.x+w2.y*a.y+w2.z*a.z+w2.w*a.w; aNX1 += w2.x*c.x+w2.y*c.y+w2.z*c.z+w2.w*c.w; }
            else           { aNH0 += w2.x*a.x+w2.y*a.y+w2.z*a.z+w2.w*a.w; aNH1 += w2.x*c.x+w2.y*c.y+w2.z*c.z+w2.w*c.w; }
        }
        float h0 = x0[INS_ + u], h1 = x1[INS_ + u];
        __syncthreads();
        { float r = sigm(aR0), z = sigm(aZ0), n = tanhx(aNX0 + r * aNH0);
          xh[rb][INS_ + u] = (1 - z) * n + z * h0; }
        { float r = sigm(aR1), z = sigm(aZ1), n = tanhx(aNX1 + r * aNH1);
          xh[rb + 1][INS_ + u] = (1 - z) * n + z * h1; }
        __syncthreads();
    };
    auto project = [&](int pos) {
        if (t < 256) {
            int r = t >> 6, m = t & 63;
            const float* wr = &wdec[m * 257]; const float* hr2 = &xh[r][INS_];
            float acc = bD;
            for (int k = 0; k < HID_; ++k) acc = fmaf(wr[k], hr2[k], acc);
            out[((size_t)(bbase + r) * LOUT_ + pos) * NUM_ + m] = acc;
            xh[r][m] = acc;
        }
    };
    for (int s = 0; s < LIN_; ++s) {
        if (t < 256) { int r = t >> 6, k = t & 63;
            xh[r][k] = input_num[((size_t)(bbase + r) * TSEQ + s) * NUM_ + k]; }
        if (t < 128) { int r = t >> 5, e = t & 31;
            xh[r][NUM_ + e] = emb_table[input_cat[(bbase + r) * TSEQ + s] * EMB_ + e]; }
        __syncthreads();
        step();
    }
    project(0);
    for (int s = 0; s < LOUT_ - 1; ++s) {
        if (t < 128) { int r = t >> 5, e = t & 31;
            xh[r][NUM_ + e] = emb_table[input_cat[(bbase + r) * TSEQ + LIN_ + s] * EMB_ + e]; }
        __syncthreads();
        step();
        project(s + 1);
    }
}

extern "C" void kernel_launch(void* const* d_in, const int* in_sizes, int n_in,
                              void* d_out, int out_size, void* d_ws, size_t ws_size,
                              hipStream_t stream) {
    const float* input_num = (const float*)d_in[0];
    const int*   input_cat = (const int*)d_in[1];
    const float* emb_table = (const float*)d_in[2];
    const float* W_ih      = (const float*)d_in[3];
    const float* W_hh      = (const float*)d_in[4];
    const float* b_ih      = (const float*)d_in[5];
    const float* b_hh      = (const float*)d_in[6];
    const float* W_dec     = (const float*)d_in[7];
    const float* b_dec     = (const float*)d_in[8];
    float* out = (float*)d_out;

    if (ws_size >= WS_NEED) {
        unsigned char* ws = (unsigned char*)d_ws;
        prep_v8<<<92, 256, 0, stream>>>(W_hh, W_dec, ws);
        gru_v8<<<NBLK, NT, 0, stream>>>(input_num, input_cat, emb_table,
                                        W_ih, W_hh, b_ih, b_hh, b_dec, ws, out);
    } else {
        gru_fallback<<<BATCH / 4, 512, 0, stream>>>(input_num, input_cat, emb_table,
                                                    W_ih, W_hh, b_ih, b_hh, W_dec, b_dec, out);
    }
}

// Round 4
// 1275.676 us; speedup vs baseline: 1.2637x; 1.2637x over previous
//
#include <hip/hip_runtime.h>

// Seq2SeqRNN v9: same math/structure as v5 (the 1097us best) but 16 waves x 1
// unit-tile at 128 regs/wave -> 4 waves/SIMD (was 8x2 @ 256 regs, 2/SIMD).
// Rounds 0-3 showed: streamed-L2 bytes/step is the dose-response cost (~15cyc/KB),
// VALU work/step is constant ~4.5K cyc, and at 2 waves/SIMD the step is
// latency-bound (13.2K cyc vs ~5K busy). v9 doubles TLP to hide the stalls.
// Weight residency per wave: regs c0..4 (60 regs), LDS c5,c6 + W_dec
// (fragment-linear, conflict-free), stream c7..c10 from L2 (2 groups of 6 frags;
// group A issued at step-top -- weights are barrier-independent).

#define BATCH 512
#define TSEQ  192
#define LIN_  96
#define LOUT_ 96
#define NUM_  64
#define EMB_  32
#define HID_  256
#define INS_  96

#define NBLK  32
#define NT    1024         // 16 waves, 4/SIMD -> 128 reg budget/wave
#define XSTR  360          // us stride: [x 0..95 | h 96..351] (v5-proven layout)

// ws: fragment-linear bf16 images, 1024 B per frag (lane l -> bytes l*16..+16).
//  stream: fid = tt*12 + g*4 + cs   (tt<16, g<3, cs<4 -> chunk 7+cs)  192 frags
//  WL    : fid = cs*48 + g*16 + tt  (cs<2 -> chunk 5+cs)               96 frags
//  WD    : fid = tt*8 + c           (tt<4, c<8)                        32 frags
#define WS_STR  0u
#define WS_WL   196608u
#define WS_WD   294912u
#define WS_NEED 327680u

typedef __attribute__((ext_vector_type(8))) short short8_t;
typedef __attribute__((ext_vector_type(4))) float float4_t;
typedef unsigned short us;

__device__ __forceinline__ us f2bf(float x) {
    unsigned u = __builtin_bit_cast(unsigned, x);
    u = (u + 0x7FFFu + ((u >> 16) & 1u)) >> 16;
    return (us)u;
}
__device__ __forceinline__ float sigm(float x)  { return 1.0f / (1.0f + __expf(-x)); }
__device__ __forceinline__ float tanhx(float x) { return 2.0f / (1.0f + __expf(-2.0f * x)) - 1.0f; }

__device__ __forceinline__ short8_t pack8(const float* v) {
    short8_t s;
    #pragma unroll
    for (int j = 0; j < 8; ++j) s[j] = (short)f2bf(v[j]);
    return s;
}

#define MFMA16(a, b, c) __builtin_amdgcn_mfma_f32_16x16x32_bf16((a), (b), (c), 0, 0, 0)

// ============ prep: fragment-linear bf16 weight images ============
__global__ void prep_v9(const float* __restrict__ W_hh, const float* __restrict__ W_dec,
                        unsigned char* __restrict__ ws) {
    us* WSi = (us*)(ws + WS_STR);
    us* WLi = (us*)(ws + WS_WL);
    us* WDi = (us*)(ws + WS_WD);
    const int idx = blockIdx.x * 256 + threadIdx.x;
    if (idx >= 320 * 64) return;
    const int f = idx >> 6, l = idx & 63;
    const int r16 = l & 15, kq8 = (l >> 4) * 8;
    float tmp[8];
    if (f < 192) {                 // stream frags: chunks 7..10 (k 224..351, all W_hh)
        const int tt = f / 12, rem = f % 12, g = rem >> 2, cs = rem & 3;
        const int grow = g * 256 + tt * 16 + r16;
        const int k = (7 + cs) * 32 + kq8;
        #pragma unroll
        for (int j = 0; j < 8; ++j) tmp[j] = W_hh[(size_t)grow * HID_ + (k - INS_) + j];
        *(short8_t*)(WSi + (size_t)f * 512 + l * 8) = pack8(tmp);
    } else if (f < 288) {          // WL frags: chunks 5,6 (k 160..223, all W_hh)
        const int f2 = f - 192, cs = f2 / 48, rem = f2 % 48, g = rem >> 4, tt = rem & 15;
        const int grow = g * 256 + tt * 16 + r16;
        const int k = (5 + cs) * 32 + kq8;
        #pragma unroll
        for (int j = 0; j < 8; ++j) tmp[j] = W_hh[(size_t)grow * HID_ + (k - INS_) + j];
        *(short8_t*)(WLi + (size_t)f2 * 512 + l * 8) = pack8(tmp);
    } else {                       // WD frags
        const int f3 = f - 288, tt = f3 >> 3, c = f3 & 7;
        const int urow = tt * 16 + r16, k = c * 32 + kq8;
        #pragma unroll
        for (int j = 0; j < 8; ++j) tmp[j] = W_dec[(size_t)urow * HID_ + k + j];
        *(short8_t*)(WDi + (size_t)f3 * 512 + l * 8) = pack8(tmp);
    }
}

// ============ main: one block per 16 batch rows, 16 waves x 16 units ============
__global__ __launch_bounds__(NT, 4) void gru_v9(
    const float* __restrict__ input_num, const int* __restrict__ input_cat,
    const float* __restrict__ emb_table,
    const float* __restrict__ W_ih, const float* __restrict__ W_hh,
    const float* __restrict__ b_ih, const float* __restrict__ b_hh,
    const float* __restrict__ b_dec,
    const unsigned char* __restrict__ ws, float* __restrict__ out)
{
    __shared__ __align__(16) us XH[16 * XSTR];     // 11.5 KB
    __shared__ __align__(16) us WLl[96 * 512];     // 96 KB  (chunks 5,6)
    __shared__ __align__(16) us WDl[32 * 512];     // 32 KB  (W_dec)

    const us* WSf = (const us*)(ws + WS_STR);

    const int t = threadIdx.x, wave = t >> 6, lane = t & 63;
    const int arow = lane & 15, quad = lane >> 4, kq = quad * 8;
    const int bb = blockIdx.x * 16;
    const int tt = wave;                           // wave owns units [16*tt, 16*tt+16)

    // ---- one-time: reg gate-weight frags, chunks 0..4 (60 regs) ----
    // c0,c1 = x/fb (W_ih k 0..63), c2 = emb (W_ih 64..95), c3,c4 = h (W_hh k 96..159)
    short8_t wfr[3][5];
    #pragma unroll
    for (int g3 = 0; g3 < 3; ++g3) {
        const int grow = g3 * HID_ + tt * 16 + arow;
        #pragma unroll
        for (int kc = 0; kc < 5; ++kc) {
            float tmp[8];
            #pragma unroll
            for (int j2 = 0; j2 < 2; ++j2) {
                const int k = kc * 32 + kq + j2 * 4;   // < 160; never straddles 96
                float4 v = (k < INS_)
                    ? *(const float4*)&W_ih[(size_t)grow * INS_ + k]
                    : *(const float4*)&W_hh[(size_t)grow * HID_ + (k - INS_)];
                tmp[j2 * 4 + 0] = v.x; tmp[j2 * 4 + 1] = v.y;
                tmp[j2 * 4 + 2] = v.z; tmp[j2 * 4 + 3] = v.w;
            }
            wfr[g3][kc] = pack8(tmp);
        }
    }

    // ---- one-time: LDS staging (fragment-linear copies) + XH zero ----
    {
        const us* WLi = (const us*)(ws + WS_WL);
        const us* WDi = (const us*)(ws + WS_WD);
        for (int c = t; c < 96 * 64; c += NT)
            *(ulonglong2*)&WLl[c * 8] = *(const ulonglong2*)&WLi[c * 8];
        for (int c = t; c < 32 * 64; c += NT)
            *(ulonglong2*)&WDl[c * 8] = *(const ulonglong2*)&WDi[c * 8];
        for (int c = t; c < 16 * XSTR; c += NT) XH[c] = 0;
    }

    // ---- biases (unit u = 16*tt + arow) ----
    const int u = tt * 16 + arow;
    const float bRr  = b_ih[u] + b_hh[u];
    const float bZr  = b_ih[HID_ + u] + b_hh[HID_ + u];
    const float bNXr = b_ih[2 * HID_ + u];
    const float bNHr = b_hh[2 * HID_ + u];
    const float bdr = (wave < 4) ? b_dec[wave * 16 + arow] : 0.0f;
    float hr[4] = {0.f, 0.f, 0.f, 0.f};
    __syncthreads();

    // ======== 191 sequential GRU steps, all block-local ========
    for (int sg = 1; sg <= 191; ++sg) {
        const int tstep = sg - 1;

        // issue stream group A (chunks 7,8) at step-top: barrier-independent weights
        short8_t svA[6];
        #pragma unroll
        for (int g = 0; g < 3; ++g) {
            svA[g * 2 + 0] = *(const short8_t*)&WSf[(size_t)(tt * 12 + g * 4 + 0) * 512 + lane * 8];
            svA[g * 2 + 1] = *(const short8_t*)&WSf[(size_t)(tt * 12 + g * 4 + 1) * 512 + lane * 8];
        }

        // (A) stage x: enc = num(0..63)+emb(64..95); dec = emb only (fb fills 0..63)
        if (sg <= 96) {
            if (t < 256) {
                const int row = t >> 4, q = t & 15;
                float4 v = *(const float4*)&input_num[((size_t)(bb + row) * TSEQ + tstep) * NUM_ + q * 4];
                ushort4 s = { f2bf(v.x), f2bf(v.y), f2bf(v.z), f2bf(v.w) };
                *(ushort4*)&XH[row * XSTR + q * 4] = s;
            } else if (t < 384) {
                const int e = t - 256, row = e >> 3, q = e & 7;
                const int cat = input_cat[(bb + row) * TSEQ + tstep];
                float4 v = *(const float4*)&emb_table[cat * EMB_ + q * 4];
                ushort4 s = { f2bf(v.x), f2bf(v.y), f2bf(v.z), f2bf(v.w) };
                *(ushort4*)&XH[row * XSTR + NUM_ + q * 4] = s;
            }
        } else if (t >= 256 && t < 384) {
            const int e = t - 256, row = e >> 3, q = e & 7;
            const int cat = input_cat[(bb + row) * TSEQ + tstep];
            float4 v = *(const float4*)&emb_table[cat * EMB_ + q * 4];
            ushort4 s = { f2bf(v.x), f2bf(v.y), f2bf(v.z), f2bf(v.w) };
            *(ushort4*)&XH[row * XSTR + NUM_ + q * 4] = s;
        }
        __syncthreads();   // B1: x + prev h visible

        // (C) decoder: out_{sg-97} = h_{sg-1} @ W_dec^T + b_dec; feedback -> XH[0..63]
        if (sg > 96) {
            float oval[4];
            if (wave < 4) {
                float4_t acc = {0.f, 0.f, 0.f, 0.f};
                #pragma unroll
                for (int c = 0; c < 8; ++c) {
                    short8_t b = *(const short8_t*)&WDl[(wave * 8 + c) * 512 + lane * 8];
                    short8_t a = *(const short8_t*)&XH[arow * XSTR + INS_ + c * 32 + kq];
                    acc = MFMA16(a, b, acc);
                }
                const int cg = wave * 16 + arow;
                #pragma unroll
                for (int i = 0; i < 4; ++i) {
                    oval[i] = acc[i] + bdr;
                    XH[(quad * 4 + i) * XSTR + cg] = f2bf(oval[i]);
                }
            }
            __syncthreads();   // B2: feedback visible
            if (wave < 4) {    // out store post-B2: drains with gate-phase slack
                const int cg = wave * 16 + arow, pos = sg - 97;
                #pragma unroll
                for (int i = 0; i < 4; ++i)
                    out[((size_t)(bb + quad * 4 + i) * LOUT_ + pos) * NUM_ + cg] = oval[i];
            }
        }

        // (D) gates: 11 chunks. regs c0..4 | LDS c5,c6 | stream c7..10 (2 groups)
        float4_t aR = {0.f,0.f,0.f,0.f}, aZ = {0.f,0.f,0.f,0.f};
        float4_t aNX = {0.f,0.f,0.f,0.f}, aNH = {0.f,0.f,0.f,0.f};
        short8_t a;
        // c0..c2: x part (reg weights)
        a = *(const short8_t*)&XH[arow * XSTR + kq];
        aR = MFMA16(a, wfr[0][0], aR); aZ = MFMA16(a, wfr[1][0], aZ); aNX = MFMA16(a, wfr[2][0], aNX);
        a = *(const short8_t*)&XH[arow * XSTR + 32 + kq];
        aR = MFMA16(a, wfr[0][1], aR); aZ = MFMA16(a, wfr[1][1], aZ); aNX = MFMA16(a, wfr[2][1], aNX);
        a = *(const short8_t*)&XH[arow * XSTR + 64 + kq];
        aR = MFMA16(a, wfr[0][2], aR); aZ = MFMA16(a, wfr[1][2], aZ); aNX = MFMA16(a, wfr[2][2], aNX);
        // c3,c4: h part (reg weights)
        a = *(const short8_t*)&XH[arow * XSTR + INS_ + 0 * 32 + kq];
        aR = MFMA16(a, wfr[0][3], aR); aZ = MFMA16(a, wfr[1][3], aZ); aNH = MFMA16(a, wfr[2][3], aNH);
        a = *(const short8_t*)&XH[arow * XSTR + INS_ + 1 * 32 + kq];
        aR = MFMA16(a, wfr[0][4], aR); aZ = MFMA16(a, wfr[1][4], aZ); aNH = MFMA16(a, wfr[2][4], aNH);
        // c5,c6: LDS B-frags (conflict-free fragment-linear)
        #pragma unroll
        for (int cs = 0; cs < 2; ++cs) {
            short8_t b0 = *(const short8_t*)&WLl[(cs * 48 + 0 * 16 + tt) * 512 + lane * 8];
            short8_t b1 = *(const short8_t*)&WLl[(cs * 48 + 1 * 16 + tt) * 512 + lane * 8];
            short8_t b2 = *(const short8_t*)&WLl[(cs * 48 + 2 * 16 + tt) * 512 + lane * 8];
            a = *(const short8_t*)&XH[arow * XSTR + INS_ + (2 + cs) * 32 + kq];
            aR = MFMA16(a, b0, aR); aZ = MFMA16(a, b1, aZ); aNH = MFMA16(a, b2, aNH);
        }
        // consume group A (c7,c8), then issue+consume group B (c9,c10)
        #pragma unroll
        for (int cs = 0; cs < 2; ++cs) {
            a = *(const short8_t*)&XH[arow * XSTR + INS_ + (4 + cs) * 32 + kq];
            aR = MFMA16(a, svA[0 * 2 + cs], aR);
            aZ = MFMA16(a, svA[1 * 2 + cs], aZ);
            aNH = MFMA16(a, svA[2 * 2 + cs], aNH);
        }
        short8_t svB[6];
        #pragma unroll
        for (int g = 0; g < 3; ++g) {
            svB[g * 2 + 0] = *(const short8_t*)&WSf[(size_t)(tt * 12 + g * 4 + 2) * 512 + lane * 8];
            svB[g * 2 + 1] = *(const short8_t*)&WSf[(size_t)(tt * 12 + g * 4 + 3) * 512 + lane * 8];
        }
        #pragma unroll
        for (int cs = 0; cs < 2; ++cs) {
            a = *(const short8_t*)&XH[arow * XSTR + INS_ + (6 + cs) * 32 + kq];
            aR = MFMA16(a, svB[0 * 2 + cs], aR);
            aZ = MFMA16(a, svB[1 * 2 + cs], aZ);
            aNH = MFMA16(a, svB[2 * 2 + cs], aNH);
        }

        // (E) pointwise GRU cell (in-register; C-frag: unit=16*tt+arow, row=quad*4+i)
        #pragma unroll
        for (int i = 0; i < 4; ++i) {
            const float r = sigm(aR[i] + bRr);
            const float z = sigm(aZ[i] + bZr);
            const float n = tanhx(aNX[i] + bNXr + r * (aNH[i] + bNHr));
            hr[i] = (1.0f - z) * n + z * hr[i];
        }

        __syncthreads();   // B3: all waves done reading XH h-cols
        #pragma unroll
        for (int i = 0; i < 4; ++i)
            XH[(quad * 4 + i) * XSTR + INS_ + tt * 16 + arow] = f2bf(hr[i]);
    }

    // ======== epilogue: out position 95 from h_191 ========
    __syncthreads();
    if (wave < 4) {
        float4_t acc = {0.f, 0.f, 0.f, 0.f};
        #pragma unroll
        for (int c = 0; c < 8; ++c) {
            short8_t b = *(const short8_t*)&WDl[(wave * 8 + c) * 512 + lane * 8];
            short8_t a = *(const short8_t*)&XH[arow * XSTR + INS_ + c * 32 + kq];
            acc = MFMA16(a, b, acc);
        }
        const int cg = wave * 16 + arow;
        #pragma unroll
        for (int i = 0; i < 4; ++i)
            out[((size_t)(bb + quad * 4 + i) * LOUT_ + 95) * NUM_ + cg] = acc[i] + bdr;
    }
}

// ============ fallback (v1 logic, known-passing fp32) if ws too small ============
__global__ __launch_bounds__(512) void gru_fallback(
    const float* __restrict__ input_num, const int* __restrict__ input_cat,
    const float* __restrict__ emb_table,
    const float* __restrict__ W_ih, const float* __restrict__ W_hh,
    const float* __restrict__ b_ih, const float* __restrict__ b_hh,
    const float* __restrict__ W_dec, const float* __restrict__ b_dec,
    float* __restrict__ out)
{
    __shared__ __align__(16) float xh[4][352];
    __shared__ float wdec[NUM_ * 257];
    const int t = threadIdx.x, bbase = blockIdx.x * 4;
    const int u = t & 255, rb = (t >> 8) * 2;
    for (int i = t; i < NUM_ * HID_; i += 512) wdec[(i >> 8) * 257 + (i & 255)] = W_dec[i];
    for (int i = t; i < 4 * HID_; i += 512) xh[i >> 8][INS_ + (i & 255)] = 0.0f;
    const float bR = b_ih[u] + b_hh[u], bZ = b_ih[256 + u] + b_hh[256 + u];
    const float bNX = b_ih[512 + u], bNH = b_hh[512 + u], bD = b_dec[t & 63];
    __syncthreads();
    auto step = [&]() {
        float aR0 = bR, aR1 = bR, aZ0 = bZ, aZ1 = bZ, aNX0 = bNX, aNX1 = bNX, aNH0 = bNH, aNH1 = bNH;
        const float* x0 = xh[rb]; const float* x1 = xh[rb + 1];
        for (int kb = 0; kb < 88; ++kb) {
            float4 w0, w1, w2; int k4 = kb * 4;
            if (k4 < INS_) {
                w0 = *(const float4*)&W_ih[(size_t)u * INS_ + k4];
                w1 = *(const float4*)&W_ih[(size_t)(256 + u) * INS_ + k4];
                w2 = *(const float4*)&W_ih[(size_t)(512 + u) * INS_ + k4];
            } else {
                int kh = k4 - INS_;
                w0 = *(const float4*)&W_hh[(size_t)u * HID_ + kh];
                w1 = *(const float4*)&W_hh[(size_t)(256 + u) * HID_ + kh];
                w2 = *(const float4*)&W_hh[(size_t)(512 + u) * HID_ + kh];
            }
            float4 a = *(const float4*)&x0[k4], c = *(const float4*)&x1[k4];
            aR0 += w0.x*a.x+w0.y*a.y+w0.z*a.z+w0.w*a.w; aR1 += w0.x*c.x+w0.y*c.y+w0.z*c.z+w0.w*c.w;
            aZ0 += w1.x*a.x+w1.y*a.y+w1.z*a.z+w1.w*a.w; aZ1 += w1.x*c.x+w1.y*c.y+w1.z*c.z+w1.w*c.w;
            if (k4 < INS_) { aNX0 += w2.x*a.x+w2.y*a.y+w2.z*a.z+w2.w*a.w; aNX1 += w2.x*c.x+w2.y*c.y+w2.z*c.z+w2.w*c.w; }
            else           { aNH0 += w2.x*a.x+w2.y*a.y+w2.z*a.z+w2.w*a.w; aNH1 += w2.x*c.x+w2.y*c.y+w2.z*c.z+w2.w*c.w; }
        }
        float h0 = x0[INS_ + u], h1 = x1[INS_ + u];
        __syncthreads();
        { float r = sigm(aR0), z = sigm(aZ0), n = tanhx(aNX0 + r * aNH0);
          xh[rb][INS_ + u] = (1 - z) * n + z * h0; }
        { float r = sigm(aR1), z = sigm(aZ1), n = tanhx(aNX1 + r * aNH1);
          xh[rb + 1][INS_ + u] = (1 - z) * n + z * h1; }
        __syncthreads();
    };
    auto project = [&](int pos) {
        if (t < 256) {
            int r = t >> 6, m = t & 63;
            const float* wr = &wdec[m * 257]; const float* hr2 = &xh[r][INS_];
            float acc = bD;
            for (int k = 0; k < HID_; ++k) acc = fmaf(wr[k], hr2[k], acc);
            out[((size_t)(bbase + r) * LOUT_ + pos) * NUM_ + m] = acc;
            xh[r][m] = acc;
        }
    };
    for (int s = 0; s < LIN_; ++s) {
        if (t < 256) { int r = t >> 6, k = t & 63;
            xh[r][k] = input_num[((size_t)(bbase + r) * TSEQ + s) * NUM_ + k]; }
        if (t < 128) { int r = t >> 5, e = t & 31;
            xh[r][NUM_ + e] = emb_table[input_cat[(bbase + r) * TSEQ + s] * EMB_ + e]; }
        __syncthreads();
        step();
    }
    project(0);
    for (int s = 0; s < LOUT_ - 1; ++s) {
        if (t < 128) { int r = t >> 5, e = t & 31;
            xh[r][NUM_ + e] = emb_table[input_cat[(bbase + r) * TSEQ + LIN_ + s] * EMB_ + e]; }
        __syncthreads();
        step();
        project(s + 1);
    }
}

extern "C" void kernel_launch(void* const* d_in, const int* in_sizes, int n_in,
                              void* d_out, int out_size, void* d_ws, size_t ws_size,
                              hipStream_t stream) {
    const float* input_num = (const float*)d_in[0];
    const int*   input_cat = (const int*)d_in[1];
    const float* emb_table = (const float*)d_in[2];
    const float* W_ih      = (const float*)d_in[3];
    const float* W_hh      = (const float*)d_in[4];
    const float* b_ih      = (const float*)d_in[5];
    const float* b_hh      = (const float*)d_in[6];
    const float* W_dec     = (const float*)d_in[7];
    const float* b_dec     = (const float*)d_in[8];
    float* out = (float*)d_out;

    if (ws_size >= WS_NEED) {
        unsigned char* ws = (unsigned char*)d_ws;
        prep_v9<<<80, 256, 0, stream>>>(W_hh, W_dec, ws);
        gru_v9<<<NBLK, NT, 0, stream>>>(input_num, input_cat, emb_table,
                                        W_ih, W_hh, b_ih, b_hh, b_dec, ws, out);
    } else {
        gru_fallback<<<BATCH / 4, 512, 0, stream>>>(input_num, input_cat, emb_table,
                                                    W_ih, W_hh, b_ih, b_hh, W_dec, b_dec, out);
    }
}

// Round 5
// 967.809 us; speedup vs baseline: 1.6658x; 1.3181x over previous
//
#include <hip/hip_runtime.h>

// Seq2SeqRNN v10: v5 skeleton (8 waves x 2 unit-tiles, 1097us best) + the three
// unconfounded micro-levers from rounds 1-4:
//  (1) ti-interleaved single k-pass: A-frag read ONCE per chunk (88 reads/CU vs
//      176). v8 proved the hoist; its regression was the stream change, not this.
//  (2) rcp/exp2 pointwise: 1.0f/(1+exp) was a full div-chain (~7 VALU each,
//      24/wave/step); v_rcp_f32 + v_exp_f32 are single instructions.
//  (3) fragment-linear weight images (v7-proven): WL/WD LDS reads and L2 streams
//      are per-lane-uniform-pattern 1KB frags -> conflict-free / coalesced.
// Residency, barriers, staging, decode fb = v5 exactly.

#define BATCH 512
#define TSEQ  192
#define LIN_  96
#define LOUT_ 96
#define NUM_  64
#define EMB_  32
#define HID_  256
#define INS_  96

#define NBLK  32
#define NT    512          // 8 waves, 2/SIMD -> 256 unified reg budget
#define XSTR  360          // us stride, XH[16][x(96)|h(256)] (v5-proven)

// ws: fragment-linear bf16 images (1024 B per frag; lane l -> bytes l*16..+16)
//  WL (LDS-staged): fid = g*32 + tt*2 + cs   (g<3, tt<16, cs<2 -> chunk 6+cs)  96 frags
//  WS (streamed)  : fid = g*48 + tt*3 + cs   (cs<3 -> chunk 8+cs)             144 frags
//  WD (W_dec)     : fid = tt*8 + c           (tt<4, c<8)                       32 frags
#define WS_WL   0u
#define WS_WS   98304u
#define WS_WD   245760u
#define WS_NEED 278528u    // same footprint as v5 (proven fits)

typedef __attribute__((ext_vector_type(8))) short short8_t;
typedef __attribute__((ext_vector_type(4))) float float4_t;
typedef unsigned short us;

__device__ __forceinline__ us f2bf(float x) {
    unsigned u = __builtin_bit_cast(unsigned, x);
    u = (u + 0x7FFFu + ((u >> 16) & 1u)) >> 16;
    return (us)u;
}
// single-instruction transcendental forms (v_rcp_f32 / v_exp_f32)
__device__ __forceinline__ float sigm(float x) {
    return __builtin_amdgcn_rcpf(1.0f + __builtin_amdgcn_exp2f(-1.44269504f * x));
}
__device__ __forceinline__ float tanhx(float x) {
    return 2.0f * __builtin_amdgcn_rcpf(1.0f + __builtin_amdgcn_exp2f(-2.88539008f * x)) - 1.0f;
}

__device__ __forceinline__ short8_t pack8(const float* v) {
    short8_t s;
    #pragma unroll
    for (int j = 0; j < 8; ++j) s[j] = (short)f2bf(v[j]);
    return s;
}

#define MFMA16(a, b, c) __builtin_amdgcn_mfma_f32_16x16x32_bf16((a), (b), (c), 0, 0, 0)

// ============ prep: fragment-linear bf16 weight images ============
__global__ void prep_v10(const float* __restrict__ W_hh, const float* __restrict__ W_dec,
                         unsigned char* __restrict__ ws) {
    us* WLi = (us*)(ws + WS_WL);
    us* WSi = (us*)(ws + WS_WS);
    us* WDi = (us*)(ws + WS_WD);
    const int idx = blockIdx.x * 256 + threadIdx.x;
    if (idx >= 272 * 64) return;
    const int f = idx >> 6, l = idx & 63;
    const int r16 = l & 15, kq8 = (l >> 4) * 8;
    float tmp[8];
    if (f < 96) {                  // WL: chunks 6,7 (k 192..255, all W_hh)
        const int g = f >> 5, rem = f & 31, tt = rem >> 1, cs = rem & 1;
        const int grow = g * 256 + tt * 16 + r16;
        const int k = (6 + cs) * 32 + kq8;
        #pragma unroll
        for (int j = 0; j < 8; ++j) tmp[j] = W_hh[(size_t)grow * HID_ + (k - INS_) + j];
        *(short8_t*)(WLi + (size_t)f * 512 + l * 8) = pack8(tmp);
    } else if (f < 240) {          // WS: chunks 8,9,10 (k 256..351, all W_hh)
        const int s = f - 96, g = s / 48, rem = s % 48, tt = rem / 3, cs = rem % 3;
        const int grow = g * 256 + tt * 16 + r16;
        const int k = (8 + cs) * 32 + kq8;
        #pragma unroll
        for (int j = 0; j < 8; ++j) tmp[j] = W_hh[(size_t)grow * HID_ + (k - INS_) + j];
        *(short8_t*)(WSi + (size_t)s * 512 + l * 8) = pack8(tmp);
    } else {                       // WD
        const int f3 = f - 240, tt = f3 >> 3, c = f3 & 7;
        const int urow = tt * 16 + r16, k = c * 32 + kq8;
        #pragma unroll
        for (int j = 0; j < 8; ++j) tmp[j] = W_dec[(size_t)urow * HID_ + k + j];
        *(short8_t*)(WDi + (size_t)f3 * 512 + l * 8) = pack8(tmp);
    }
}

// ============ main: one self-sufficient block per 16 batch rows ============
__global__ __launch_bounds__(NT, 2) void gru_v10(
    const float* __restrict__ input_num, const int* __restrict__ input_cat,
    const float* __restrict__ emb_table,
    const float* __restrict__ W_ih, const float* __restrict__ W_hh,
    const float* __restrict__ b_ih, const float* __restrict__ b_hh,
    const float* __restrict__ b_dec,
    const unsigned char* __restrict__ ws, float* __restrict__ out)
{
    __shared__ __align__(16) us XH[16 * XSTR];     // 11.25 KB
    __shared__ __align__(16) us WLl[96 * 512];     // 96 KB (chunks 6,7)
    __shared__ __align__(16) us WDl[32 * 512];     // 32 KB (W_dec)

    const us* WSf = (const us*)(ws + WS_WS);

    const int t = threadIdx.x, wave = t >> 6, lane = t & 63;
    const int arow = lane & 15, quad = lane >> 4, kq = quad * 8;
    const int bb = blockIdx.x * 16;
    const int tt0 = 2 * wave, tt1 = 2 * wave + 1;

    // ---- one-time: reg gate-weight frags, chunks 0..5 (144 regs, v5-proven) ----
    short8_t wfr[2][3][6];
    #pragma unroll
    for (int ti = 0; ti < 2; ++ti) {
        #pragma unroll
        for (int g3 = 0; g3 < 3; ++g3) {
            const int grow = g3 * HID_ + 32 * wave + 16 * ti + arow;
            #pragma unroll
            for (int kc = 0; kc < 6; ++kc) {
                float tmp[8];
                #pragma unroll
                for (int j2 = 0; j2 < 2; ++j2) {
                    const int k = kc * 32 + kq + j2 * 4;   // < 192; never straddles 96
                    float4 v = (k < INS_)
                        ? *(const float4*)&W_ih[(size_t)grow * INS_ + k]
                        : *(const float4*)&W_hh[(size_t)grow * HID_ + (k - INS_)];
                    tmp[j2 * 4 + 0] = v.x; tmp[j2 * 4 + 1] = v.y;
                    tmp[j2 * 4 + 2] = v.z; tmp[j2 * 4 + 3] = v.w;
                }
                wfr[ti][g3][kc] = pack8(tmp);
            }
        }
    }

    // ---- one-time: LDS staging (fragment-linear copies) + XH zero ----
    {
        const us* WLi = (const us*)(ws + WS_WL);
        const us* WDi = (const us*)(ws + WS_WD);
        for (int c = t; c < 96 * 64; c += NT)
            *(ulonglong2*)&WLl[c * 8] = *(const ulonglong2*)&WLi[c * 8];
        for (int c = t; c < 32 * 64; c += NT)
            *(ulonglong2*)&WDl[c * 8] = *(const ulonglong2*)&WDi[c * 8];
        for (int c = t; c < 16 * XSTR; c += NT) XH[c] = 0;
    }

    // ---- biases (unit u = 32w + 16ti + arow) ----
    float bRr[2], bZr[2], bNXr[2], bNHr[2];
    #pragma unroll
    for (int ti = 0; ti < 2; ++ti) {
        const int u = 32 * wave + 16 * ti + arow;
        bRr[ti]  = b_ih[u] + b_hh[u];
        bZr[ti]  = b_ih[HID_ + u] + b_hh[HID_ + u];
        bNXr[ti] = b_ih[2 * HID_ + u];
        bNHr[ti] = b_hh[2 * HID_ + u];
    }
    const float bdr = (wave < 4) ? b_dec[wave * 16 + arow] : 0.0f;
    float hr[2][4] = {{0.f,0.f,0.f,0.f},{0.f,0.f,0.f,0.f}};
    __syncthreads();

    // ======== 191 sequential GRU steps, all block-local ========
    for (int sg = 1; sg <= 191; ++sg) {
        const int tstep = sg - 1;

        // (A) stage x: enc = num(0..63)+emb(64..95); dec = emb only (fb fills 0..63)
        if (sg <= 96) {
            if (t < 256) {
                const int row = t >> 4, q = t & 15;
                float4 v = *(const float4*)&input_num[((size_t)(bb + row) * TSEQ + tstep) * NUM_ + q * 4];
                ushort4 s = { f2bf(v.x), f2bf(v.y), f2bf(v.z), f2bf(v.w) };
                *(ushort4*)&XH[row * XSTR + q * 4] = s;
            } else if (t < 384) {
                const int e = t - 256, row = e >> 3, q = e & 7;
                const int cat = input_cat[(bb + row) * TSEQ + tstep];
                float4 v = *(const float4*)&emb_table[cat * EMB_ + q * 4];
                ushort4 s = { f2bf(v.x), f2bf(v.y), f2bf(v.z), f2bf(v.w) };
                *(ushort4*)&XH[row * XSTR + NUM_ + q * 4] = s;
            }
        } else if (t < 128) {
            const int row = t >> 3, q = t & 7;
            const int cat = input_cat[(bb + row) * TSEQ + tstep];
            float4 v = *(const float4*)&emb_table[cat * EMB_ + q * 4];
            ushort4 s = { f2bf(v.x), f2bf(v.y), f2bf(v.z), f2bf(v.w) };
            *(ushort4*)&XH[row * XSTR + NUM_ + q * 4] = s;
        }
        __syncthreads();   // B1: x + prev h visible

        // (C) decoder: out_{sg-97} = h_{sg-1} @ W_dec^T + b_dec; feedback -> XH[0..63]
        if (sg > 96) {
            if (wave < 4) {
                float4_t acc = {0.f, 0.f, 0.f, 0.f};
                #pragma unroll
                for (int c = 0; c < 8; ++c) {
                    short8_t b = *(const short8_t*)&WDl[(wave * 8 + c) * 512 + lane * 8];
                    short8_t a = *(const short8_t*)&XH[arow * XSTR + INS_ + c * 32 + kq];
                    acc = MFMA16(a, b, acc);
                }
                const int cg = wave * 16 + arow, pos = sg - 97;
                #pragma unroll
                for (int i = 0; i < 4; ++i) {
                    const int row = quad * 4 + i;
                    const float val = acc[i] + bdr;
                    XH[row * XSTR + cg] = f2bf(val);
                    out[((size_t)(bb + row) * LOUT_ + pos) * NUM_ + cg] = val;
                }
            }
            __syncthreads();   // B2: feedback visible
        }

        // (D) gates: ti-interleaved single k-pass; A-frag read ONCE per chunk
        float4_t aR[2]  = {{0.f,0.f,0.f,0.f},{0.f,0.f,0.f,0.f}};
        float4_t aZ[2]  = {{0.f,0.f,0.f,0.f},{0.f,0.f,0.f,0.f}};
        float4_t aNX[2] = {{0.f,0.f,0.f,0.f},{0.f,0.f,0.f,0.f}};
        float4_t aNH[2] = {{0.f,0.f,0.f,0.f},{0.f,0.f,0.f,0.f}};

        // issue stream group 1: chunks 8,9 x 3 gates x both tiles (12 loads)
        short8_t s8[6], s9[6];   // [g*2 + ti]
        #pragma unroll
        for (int g = 0; g < 3; ++g) {
            s8[g * 2 + 0] = *(const short8_t*)&WSf[(size_t)(g * 48 + tt0 * 3 + 0) * 512 + lane * 8];
            s8[g * 2 + 1] = *(const short8_t*)&WSf[(size_t)(g * 48 + tt1 * 3 + 0) * 512 + lane * 8];
            s9[g * 2 + 0] = *(const short8_t*)&WSf[(size_t)(g * 48 + tt0 * 3 + 1) * 512 + lane * 8];
            s9[g * 2 + 1] = *(const short8_t*)&WSf[(size_t)(g * 48 + tt1 * 3 + 1) * 512 + lane * 8];
        }

        // chunks 0..5: reg weights (c0,c1=x, c2=emb, c3..5=h)
        #pragma unroll
        for (int kc = 0; kc < 6; ++kc) {
            short8_t a = *(const short8_t*)&XH[arow * XSTR + kc * 32 + kq];
            #pragma unroll
            for (int ti = 0; ti < 2; ++ti) {
                aR[ti] = MFMA16(a, wfr[ti][0][kc], aR[ti]);
                aZ[ti] = MFMA16(a, wfr[ti][1][kc], aZ[ti]);
                if (kc < 3) aNX[ti] = MFMA16(a, wfr[ti][2][kc], aNX[ti]);
                else        aNH[ti] = MFMA16(a, wfr[ti][2][kc], aNH[ti]);
            }
        }
        // chunks 6,7: LDS (fragment-linear, conflict-free)
        #pragma unroll
        for (int cs = 0; cs < 2; ++cs) {
            short8_t a = *(const short8_t*)&XH[arow * XSTR + (6 + cs) * 32 + kq];
            #pragma unroll
            for (int ti = 0; ti < 2; ++ti) {
                const int tt = tt0 + ti;
                short8_t b0 = *(const short8_t*)&WLl[(0 * 32 + tt * 2 + cs) * 512 + lane * 8];
                short8_t b1 = *(const short8_t*)&WLl[(1 * 32 + tt * 2 + cs) * 512 + lane * 8];
                short8_t b2 = *(const short8_t*)&WLl[(2 * 32 + tt * 2 + cs) * 512 + lane * 8];
                aR[ti] = MFMA16(a, b0, aR[ti]);
                aZ[ti] = MFMA16(a, b1, aZ[ti]);
                aNH[ti] = MFMA16(a, b2, aNH[ti]);
            }
        }
        // issue stream group 2: chunk 10 (6 loads)
        short8_t s10[6];
        #pragma unroll
        for (int g = 0; g < 3; ++g) {
            s10[g * 2 + 0] = *(const short8_t*)&WSf[(size_t)(g * 48 + tt0 * 3 + 2) * 512 + lane * 8];
            s10[g * 2 + 1] = *(const short8_t*)&WSf[(size_t)(g * 48 + tt1 * 3 + 2) * 512 + lane * 8];
        }
        // chunks 8,9,10: consume streamed frags
        {
            short8_t a = *(const short8_t*)&XH[arow * XSTR + 8 * 32 + kq];
            #pragma unroll
            for (int ti = 0; ti < 2; ++ti) {
                aR[ti] = MFMA16(a, s8[0 * 2 + ti], aR[ti]);
                aZ[ti] = MFMA16(a, s8[1 * 2 + ti], aZ[ti]);
                aNH[ti] = MFMA16(a, s8[2 * 2 + ti], aNH[ti]);
            }
            a = *(const short8_t*)&XH[arow * XSTR + 9 * 32 + kq];
            #pragma unroll
            for (int ti = 0; ti < 2; ++ti) {
                aR[ti] = MFMA16(a, s9[0 * 2 + ti], aR[ti]);
                aZ[ti] = MFMA16(a, s9[1 * 2 + ti], aZ[ti]);
                aNH[ti] = MFMA16(a, s9[2 * 2 + ti], aNH[ti]);
            }
            a = *(const short8_t*)&XH[arow * XSTR + 10 * 32 + kq];
            #pragma unroll
            for (int ti = 0; ti < 2; ++ti) {
                aR[ti] = MFMA16(a, s10[0 * 2 + ti], aR[ti]);
                aZ[ti] = MFMA16(a, s10[1 * 2 + ti], aZ[ti]);
                aNH[ti] = MFMA16(a, s10[2 * 2 + ti], aNH[ti]);
            }
        }

        // (E) pointwise GRU cell (rcp/exp2 single-instruction forms)
        #pragma unroll
        for (int ti = 0; ti < 2; ++ti) {
            #pragma unroll
            for (int i = 0; i < 4; ++i) {
                const float r = sigm(aR[ti][i] + bRr[ti]);
                const float z = sigm(aZ[ti][i] + bZr[ti]);
                const float n = tanhx(aNX[ti][i] + bNXr[ti] + r * (aNH[ti][i] + bNHr[ti]));
                hr[ti][i] = (1.0f - z) * n + z * hr[ti][i];
            }
        }

        __syncthreads();   // B3: all waves done reading XH h-cols
        #pragma unroll
        for (int ti = 0; ti < 2; ++ti) {
            #pragma unroll
            for (int i = 0; i < 4; ++i)
                XH[(quad * 4 + i) * XSTR + INS_ + 32 * wave + 16 * ti + arow] = f2bf(hr[ti][i]);
        }
    }

    // ======== epilogue: out position 95 from h_191 ========
    __syncthreads();
    if (wave < 4) {
        float4_t acc = {0.f, 0.f, 0.f, 0.f};
        #pragma unroll
        for (int c = 0; c < 8; ++c) {
            short8_t b = *(const short8_t*)&WDl[(wave * 8 + c) * 512 + lane * 8];
            short8_t a = *(const short8_t*)&XH[arow * XSTR + INS_ + c * 32 + kq];
            acc = MFMA16(a, b, acc);
        }
        const int cg = wave * 16 + arow;
        #pragma unroll
        for (int i = 0; i < 4; ++i) {
            const int row = quad * 4 + i;
            out[((size_t)(bb + row) * LOUT_ + 95) * NUM_ + cg] = acc[i] + bdr;
        }
    }
}

// ============ fallback (v1 logic, known-passing fp32) if ws too small ============
__global__ __launch_bounds__(512) void gru_fallback(
    const float* __restrict__ input_num, const int* __restrict__ input_cat,
    const float* __restrict__ emb_table,
    const float* __restrict__ W_ih, const float* __restrict__ W_hh,
    const float* __restrict__ b_ih, const float* __restrict__ b_hh,
    const float* __restrict__ W_dec, const float* __restrict__ b_dec,
    float* __restrict__ out)
{
    __shared__ __align__(16) float xh[4][352];
    __shared__ float wdec[NUM_ * 257];
    const int t = threadIdx.x, bbase = blockIdx.x * 4;
    const int u = t & 255, rb = (t >> 8) * 2;
    for (int i = t; i < NUM_ * HID_; i += 512) wdec[(i >> 8) * 257 + (i & 255)] = W_dec[i];
    for (int i = t; i < 4 * HID_; i += 512) xh[i >> 8][INS_ + (i & 255)] = 0.0f;
    const float bR = b_ih[u] + b_hh[u], bZ = b_ih[256 + u] + b_hh[256 + u];
    const float bNX = b_ih[512 + u], bNH = b_hh[512 + u], bD = b_dec[t & 63];
    __syncthreads();
    auto sg_ = [](float x) { return 1.0f / (1.0f + __expf(-x)); };
    auto th_ = [](float x) { return 2.0f / (1.0f + __expf(-2.0f * x)) - 1.0f; };
    auto step = [&]() {
        float aR0 = bR, aR1 = bR, aZ0 = bZ, aZ1 = bZ, aNX0 = bNX, aNX1 = bNX, aNH0 = bNH, aNH1 = bNH;
        const float* x0 = xh[rb]; const float* x1 = xh[rb + 1];
        for (int kb = 0; kb < 88; ++kb) {
            float4 w0, w1, w2; int k4 = kb * 4;
            if (k4 < INS_) {
                w0 = *(const float4*)&W_ih[(size_t)u * INS_ + k4];
                w1 = *(const float4*)&W_ih[(size_t)(256 + u) * INS_ + k4];
                w2 = *(const float4*)&W_ih[(size_t)(512 + u) * INS_ + k4];
            } else {
                int kh = k4 - INS_;
                w0 = *(const float4*)&W_hh[(size_t)u * HID_ + kh];
                w1 = *(const float4*)&W_hh[(size_t)(256 + u) * HID_ + kh];
                w2 = *(const float4*)&W_hh[(size_t)(512 + u) * HID_ + kh];
            }
            float4 a = *(const float4*)&x0[k4], c = *(const float4*)&x1[k4];
            aR0 += w0.x*a.x+w0.y*a.y+w0.z*a.z+w0.w*a.w; aR1 += w0.x*c.x+w0.y*c.y+w0.z*c.z+w0.w*c.w;
            aZ0 += w1.x*a.x+w1.y*a.y+w1.z*a.z+w1.w*a.w; aZ1 += w1.x*c.x+w1.y*c.y+w1.z*c.z+w1.w*c.w;
            if (k4 < INS_) { aNX0 += w2.x*a.x+w2.y*a.y+w2.z*a.z+w2.w*a.w; aNX1 += w2.x*c.x+w2.y*c.y+w2.z*c.z+w2.w*c.w; }
            else           { aNH0 += w2.x*a.x+w2.y*a.y+w2.z*a.z+w2.w*a.w; aNH1 += w2.x*c.x+w2.y*c.y+w2.z*c.z+w2.w*c.w; }
        }
        float h0 = x0[INS_ + u], h1 = x1[INS_ + u];
        __syncthreads();
        { float r = sg_(aR0), z = sg_(aZ0), n = th_(aNX0 + r * aNH0);
          xh[rb][INS_ + u] = (1 - z) * n + z * h0; }
        { float r = sg_(aR1), z = sg_(aZ1), n = th_(aNX1 + r * aNH1);
          xh[rb + 1][INS_ + u] = (1 - z) * n + z * h1; }
        __syncthreads();
    };
    auto project = [&](int pos) {
        if (t < 256) {
            int r = t >> 6, m = t & 63;
            const float* wr = &wdec[m * 257]; const float* hr2 = &xh[r][INS_];
            float acc = bD;
            for (int k = 0; k < HID_; ++k) acc = fmaf(wr[k], hr2[k], acc);
            out[((size_t)(bbase + r) * LOUT_ + pos) * NUM_ + m] = acc;
            xh[r][m] = acc;
        }
    };
    for (int s = 0; s < LIN_; ++s) {
        if (t < 256) { int r = t >> 6, k = t & 63;
            xh[r][k] = input_num[((size_t)(bbase + r) * TSEQ + s) * NUM_ + k]; }
        if (t < 128) { int r = t >> 5, e = t & 31;
            xh[r][NUM_ + e] = emb_table[input_cat[(bbase + r) * TSEQ + s] * EMB_ + e]; }
        __syncthreads();
        step();
    }
    project(0);
    for (int s = 0; s < LOUT_ - 1; ++s) {
        if (t < 128) { int r = t >> 5, e = t & 31;
            xh[r][NUM_ + e] = emb_table[input_cat[(bbase + r) * TSEQ + LIN_ + s] * EMB_ + e]; }
        __syncthreads();
        step();
        project(s + 1);
    }
}

extern "C" void kernel_launch(void* const* d_in, const int* in_sizes, int n_in,
                              void* d_out, int out_size, void* d_ws, size_t ws_size,
                              hipStream_t stream) {
    const float* input_num = (const float*)d_in[0];
    const int*   input_cat = (const int*)d_in[1];
    const float* emb_table = (const float*)d_in[2];
    const float* W_ih      = (const float*)d_in[3];
    const float* W_hh      = (const float*)d_in[4];
    const float* b_ih      = (const float*)d_in[5];
    const float* b_hh      = (const float*)d_in[6];
    const float* W_dec     = (const float*)d_in[7];
    const float* b_dec     = (const float*)d_in[8];
    float* out = (float*)d_out;

    if (ws_size >= WS_NEED) {
        unsigned char* ws = (unsigned char*)d_ws;
        prep_v10<<<68, 256, 0, stream>>>(W_hh, W_dec, ws);
        gru_v10<<<NBLK, NT, 0, stream>>>(input_num, input_cat, emb_table,
                                         W_ih, W_hh, b_ih, b_hh, b_dec, ws, out);
    } else {
        gru_fallback<<<BATCH / 4, 512, 0, stream>>>(input_num, input_cat, emb_table,
                                                    W_ih, W_hh, b_ih, b_hh, W_dec, b_dec, out);
    }
}